// Round 8
// baseline (2747.592 us; speedup 1.0000x reference)
//
#include <hip/hip_runtime.h>
#include <hip/hip_bf16.h>

// QJL with orthogonal projections, MI355X (gfx950).
// out[t] = scale * sum_m sign(K[t]·S[m]) * (Q[t]·S[m]),  t in [0,131072)
//
// R12 structure (1-pass sign dot + exact-sign fixup kernel):
//  - OCCUPANCY LAW (R7-R11 evidence + m69): VGPR pool = 512 regs/SIMD.
//    At 128 total regs/wave (64 acc AGPR + 64 VGPR) the cap is 4 waves/SIMD
//    = 50%; measured 35% (ramp/tail/stragglers). Registers bind, not LDS.
//  - R12 halves the WORK per wave instead of rescheduling it:
//    * C = K·S^T computed in ONE bf16 pass (was 3-pass hi/lo).
//      err sigma ~= sqrt(128)*2^-9*sqrt(2/3) ~= 0.018; TAU widened to
//      0.125 (~7 sigma) -> missed-sign P ~ 1e-11 (never).
//    * Borderline |C| < TAU (~75K of 8.4M, 0.9%) are RECORDED (tok,m,qp)
//      to a workspace list (wave-coalesced atomic + 8B store) and
//      contribute 0; a separate fixup kernel resolves them with the
//      proven OpenBLAS-chain ref_sign (exact reference sign, np.sign(0)=0)
//      IN PARALLEL (~2-3us) and atomicAdds s*qp*SCALE into out.
//      -> the ~2000cy serial ref_sign chains and their block-barrier
//      amplification leave the main kernel entirely.
//    * S-lo table gone (16 S loads/wave, was 32; -16 VGPR fragments),
//      K-lo staging gone (LDS 26.6->17.9 KB, -33% staging VALU),
//      MFMAs 128->64 per wave.
//  - accQ path unchanged (1-pass bf16) -> absmax unchanged (0.03125).
//  - ws layout: shi table 64KB | counter 16B | records REC_CAP x 8B.
//    prep kernel builds the table and zeroes the counter each launch.
//  - Fallback (ws too small): 1-pass + inline ref_sign (correct, slow,
//    never taken in practice).

#define DIM        128
#define NPROJ      256
#define TILE_T     32
#define NWG        4096        // NTOK / TILE_T
#define LDS_STRIDE 136         // bf16 elems; m97-proven padded layout
#define TAU_W      0.125f      // ~7 sigma of 1-pass bf16 dot error
#define REC_CAP    131072u     // record capacity (expect ~75K, 1.77x margin)
#define SCALE      0.0048957583489668f  // sqrt(pi/2)/256

typedef __attribute__((ext_vector_type(8))) short short8;  // 8 bf16 = 4 VGPRs
typedef __attribute__((ext_vector_type(4))) float f32x4;

static __device__ __forceinline__ unsigned short bf16_rne(float x){
    unsigned int u = __builtin_bit_cast(unsigned int, x);
    u += 0x7FFFu + ((u >> 16) & 1u);
    return (unsigned short)(u >> 16);
}

// Reference-exact sign: OpenBLAS sgemm per-element k-chain, fp32 FMA,
// ascending d. Returns np.sign(dot) in {-1, 0, +1}.  [verified round 5]
// The sequential order is the correctness contract — do not reorder.
static __device__ __attribute__((noinline))
float ref_sign(const float* __restrict__ Kg, const float* __restrict__ S,
               int tok, int m){
    const float4* kr = (const float4*)(Kg + (size_t)tok * DIM);
    const float4* sr = (const float4*)(S  + (size_t)m   * DIM);
    float acc = 0.f;
#pragma unroll 4
    for (int d = 0; d < DIM/4; ++d){
        float4 k4 = kr[d];
        float4 s4 = sr[d];
        acc = __builtin_fmaf(k4.x, s4.x, acc);
        acc = __builtin_fmaf(k4.y, s4.y, acc);
        acc = __builtin_fmaf(k4.z, s4.z, acc);
        acc = __builtin_fmaf(k4.w, s4.w, acc);
    }
    return (acc > 0.f) ? 1.f : ((acc < 0.f) ? -1.f : 0.f);
}

// S -> bf16 hi table, swizzled to fragment order:
//   tab[(((g*4+ks)*4+ms)*64 + lane)*8 + e] = conv(S[g*64+ms*16+(lane&15)]
//                                                  [ks*32+(lane>>4)*8+e])
// Also zeroes the record counter (runs before the main kernel each launch).
__global__ void prep_s_kernel(const float* __restrict__ S,
                              unsigned short* __restrict__ shi,
                              unsigned int* __restrict__ counter){
    int t    = blockIdx.x * 256 + threadIdx.x;   // 4096 threads
    if (t == 0) *counter = 0u;
    int lane = t & 63;
    int ms   = (t >> 6) & 3;
    int ks   = (t >> 8) & 3;
    int g    = (t >> 10) & 3;
    int m    = g*64 + ms*16 + (lane & 15);
    int d    = ks*32 + (lane >> 4)*8;
    const float4* p = (const float4*)(S + (size_t)m*DIM + d);
    float4 x0 = p[0], x1 = p[1];
    float xs[8] = {x0.x,x0.y,x0.z,x0.w, x1.x,x1.y,x1.z,x1.w};
    size_t base = ((size_t)t) * 8;
    unsigned long long h0=0, h1=0;
#pragma unroll
    for (int e = 0; e < 4; ++e)
        h0 |= (unsigned long long)bf16_rne(xs[e])   << (16*e);
#pragma unroll
    for (int e = 0; e < 4; ++e)
        h1 |= (unsigned long long)bf16_rne(xs[4+e]) << (16*e);
    *(unsigned long long*)(shi + base)     = h0;
    *(unsigned long long*)(shi + base + 4) = h1;
}

// Load this wave's hi A-fragments for one ks: table path (coalesced 16B/lane)
// or inline-convert fallback from fp32 S.
template<bool USE_TAB>
static __device__ __forceinline__
void load_afrags(const unsigned short* __restrict__ shi_tab,
                 const float* __restrict__ S,
                 int wave, int ks, int l16, int quad, int lane,
                 short8 ah[4]){
    if (USE_TAB){
#pragma unroll
        for (int ms = 0; ms < 4; ++ms){
            size_t off = ((size_t)((wave*4 + ks)*4 + ms)*64 + lane)*8;
            ah[ms] = *(const short8*)(shi_tab + off);
        }
    } else {
#pragma unroll
        for (int ms = 0; ms < 4; ++ms){
            const float4* p = (const float4*)(S + (size_t)(wave*64 + ms*16 + l16)*DIM
                                              + ks*32 + quad*8);
            float4 x0 = p[0], x1 = p[1];
            float xs[8] = {x0.x,x0.y,x0.z,x0.w, x1.x,x1.y,x1.z,x1.w};
            short8 h;
#pragma unroll
            for (int e = 0; e < 8; ++e)
                h[e] = (short)bf16_rne(xs[e]);
            ah[ms] = h;
        }
    }
}

template<bool USE_TAB>
__global__ __launch_bounds__(256, 4)
void qjl_kernel(const float* __restrict__ Qg, const float* __restrict__ Kg,
                const float* __restrict__ S,
                const unsigned short* __restrict__ shi_tab,
                unsigned int* __restrict__ counter,
                unsigned long long* __restrict__ records,
                float* __restrict__ out)
{
    __shared__ unsigned short khi[TILE_T * LDS_STRIDE];
    __shared__ unsigned short qhi[TILE_T * LDS_STRIDE];
    __shared__ float red[4][TILE_T];

    const int tid  = threadIdx.x;
    const int wave = tid >> 6;
    const int lane = tid & 63;
    const int l16  = lane & 15;
    const int quad = lane >> 4;
    const int tok0 = blockIdx.x * TILE_T;

    // ---- stage: 32 tokens of K and Q, fp32 -> bf16 hi in LDS ----
    {
        const float4* ksrc = (const float4*)(Kg + (size_t)tok0 * DIM);
        const float4* qsrc = (const float4*)(Qg + (size_t)tok0 * DIM);
        float4 kv[4], qv[4];
#pragma unroll
        for (int j = 0; j < 4; ++j){ kv[j] = ksrc[tid + j*256]; qv[j] = qsrc[tid + j*256]; }
#pragma unroll
        for (int j = 0; j < 4; ++j){
            int i   = tid + j*256;
            int row = i >> 5;
            int c   = i & 31;
            float kx[4] = {kv[j].x, kv[j].y, kv[j].z, kv[j].w};
            float qx[4] = {qv[j].x, qv[j].y, qv[j].z, qv[j].w};
            unsigned long long hp = 0, qp = 0;
#pragma unroll
            for (int e = 0; e < 4; ++e){
                hp |= (unsigned long long)bf16_rne(kx[e]) << (16*e);
                qp |= (unsigned long long)bf16_rne(qx[e]) << (16*e);
            }
            int base = row * LDS_STRIDE + c*4;
            *(unsigned long long*)(khi + base) = hp;
            *(unsigned long long*)(qhi + base) = qp;
        }
    }
    __syncthreads();

    // ---- fused k-loop: accC = K·S^T (1-pass), accQ = Q·S^T (1-pass) ----
    f32x4 accC[4][2];
    f32x4 accQ[4][2];
#pragma unroll
    for (int ms = 0; ms < 4; ++ms)
#pragma unroll
        for (int ts = 0; ts < 2; ++ts){
            accC[ms][ts] = (f32x4){0.f,0.f,0.f,0.f};
            accQ[ms][ts] = (f32x4){0.f,0.f,0.f,0.f};
        }

#pragma unroll
    for (int ks = 0; ks < 4; ++ks){
        short8 ah[4];
        load_afrags<USE_TAB>(shi_tab, S, wave, ks, l16, quad, lane, ah);
#pragma unroll
        for (int ts = 0; ts < 2; ++ts){
            const int off = (ts*16 + l16) * LDS_STRIDE + ks*32 + quad*8;
            short8 bk = *(const short8*)(khi + off);
            short8 bq = *(const short8*)(qhi + off);
#pragma unroll
            for (int ms = 0; ms < 4; ++ms)
                accC[ms][ts] = __builtin_amdgcn_mfma_f32_16x16x32_bf16(ah[ms], bk, accC[ms][ts], 0,0,0);
#pragma unroll
            for (int ms = 0; ms < 4; ++ms)
                accQ[ms][ts] = __builtin_amdgcn_mfma_f32_16x16x32_bf16(ah[ms], bq, accQ[ms][ts], 0,0,0);
        }
    }

    // ---- epilogue: sign from 1-pass accC; |C| < TAU_W -> record for the
    //      fixup kernel (contribute 0 here). C/D layout: col(token)=lane&15,
    //      row(m)=quad*4+r ----
    float part0 = 0.f, part1 = 0.f;
#pragma unroll
    for (int ts = 0; ts < 2; ++ts){
#pragma unroll
        for (int ms = 0; ms < 4; ++ms){
#pragma unroll
            for (int r = 0; r < 4; ++r){
                float c  = accC[ms][ts][r];
                float qp = accQ[ms][ts][r];
                float sv;
                if (__builtin_fabsf(c) >= TAU_W){
                    sv = (c > 0.f) ? qp : -qp;   // c != 0 here
                } else {
                    int tok = tok0 + ts*16 + l16;
                    int m   = wave*64 + ms*16 + quad*4 + r;
                    if (USE_TAB){
                        unsigned int idx = atomicAdd(counter, 1u);
                        if (idx < REC_CAP){
                            unsigned int key = ((unsigned int)tok << 8) | (unsigned int)m;
                            records[idx] =
                                ((unsigned long long)__builtin_bit_cast(unsigned int, qp) << 32)
                                | (unsigned long long)key;
                            sv = 0.f;
                        } else {
                            float s = ref_sign(Kg, S, tok, m);   // overflow safety net
                            sv = s * qp;
                        }
                    } else {
                        float s = ref_sign(Kg, S, tok, m);       // no-workspace path
                        sv = s * qp;
                    }
                }
                if (ts) part1 += sv; else part0 += sv;
            }
        }
    }

    // ---- reduce: token t in lanes {l16, l16+16, l16+32, l16+48} ----
    part0 += __shfl_xor(part0, 16, 64);
    part0 += __shfl_xor(part0, 32, 64);
    part1 += __shfl_xor(part1, 16, 64);
    part1 += __shfl_xor(part1, 32, 64);
    if (quad == 0){
        red[wave][l16]      = part0;
        red[wave][16 + l16] = part1;
    }
    __syncthreads();
    if (tid < TILE_T)
        out[tok0 + tid] = SCALE * (red[0][tid] + red[1][tid] + red[2][tid] + red[3][tid]);
}

// Resolve recorded borderline signs with the exact reference chain, in
// parallel (one record per lane), and accumulate into out.
__global__ void fixup_kernel(const float* __restrict__ Kg,
                             const float* __restrict__ S,
                             const unsigned int* __restrict__ counter,
                             const unsigned long long* __restrict__ records,
                             float* __restrict__ out){
    unsigned int n = *counter;
    if (n > REC_CAP) n = REC_CAP;
    unsigned int stride = gridDim.x * blockDim.x;
    for (unsigned int i = blockIdx.x * blockDim.x + threadIdx.x; i < n; i += stride){
        unsigned long long rec = records[i];
        unsigned int key = (unsigned int)rec;
        float qp = __builtin_bit_cast(float, (unsigned int)(rec >> 32));
        int tok = (int)(key >> 8);
        int m   = (int)(key & 255u);
        float s = ref_sign(Kg, S, tok, m);
        if (s != 0.f)
            atomicAdd(&out[tok], SCALE * s * qp);
    }
}

extern "C" void kernel_launch(void* const* d_in, const int* in_sizes, int n_in,
                              void* d_out, int out_size, void* d_ws, size_t ws_size,
                              hipStream_t stream){
    const float* Qg = (const float*)d_in[0];
    const float* Kg = (const float*)d_in[1];
    const float* S  = (const float*)d_in[2];
    float* out = (float*)d_out;

    const size_t tab_bytes = (size_t)NPROJ * DIM * sizeof(unsigned short);  // 64 KiB
    const size_t need = tab_bytes + 16 + (size_t)REC_CAP * 8;               // ~1.06 MiB

    if (d_ws && ws_size >= need){
        unsigned short* shi = (unsigned short*)d_ws;
        unsigned int* counter = (unsigned int*)((char*)d_ws + tab_bytes);
        unsigned long long* recs = (unsigned long long*)((char*)d_ws + tab_bytes + 16);
        prep_s_kernel<<<16, 256, 0, stream>>>(S, shi, counter);
        qjl_kernel<true><<<NWG, 256, 0, stream>>>(Qg, Kg, S, shi, counter, recs, out);
        fixup_kernel<<<256, 256, 0, stream>>>(Kg, S, counter, recs, out);
    } else {
        qjl_kernel<false><<<NWG, 256, 0, stream>>>(Qg, Kg, S, nullptr, nullptr, nullptr, out);
    }
}

// Round 9
// 203.825 us; speedup vs baseline: 13.4802x; 13.4802x over previous
//
#include <hip/hip_runtime.h>
#include <hip/hip_bf16.h>

// QJL with orthogonal projections, MI355X (gfx950).
// out[t] = scale * sum_m sign(K[t]·S[m]) * (Q[t]·S[m]),  t in [0,131072)
//
// R13 structure (1-pass sign dot + per-block contention-free recording):
//  - R12 post-mortem: numerics validated (absmax 0.03125 unchanged) but the
//    SINGLE global record counter serialized ~295K (=33.5M x 0.88%, R12
//    undercounted by 4x) cross-XCD same-address atomics ~10ns each = 2.6ms.
//  - R13: per-block recording. LDS counter (block-local atomic, ~ns) +
//    private region records[block*BCAP + idx]; counts[block] written once.
//    lambda = 72 borderline/block; BCAP tiered {128,64,32,16} by actual
//    ws_size (R12 proved ws >= 1.06MB -> BCAP>=16 guaranteed). Block
//    overflow -> proven inline ref_sign (P~0 at BCAP=128).
//  - fixup kernel: 4096 blocks x 128 thr; thread j of block b resolves
//    record j if j < counts[b] via the exact OpenBLAS-chain ref_sign
//    (np.sign(0)=0) and atomicAdds SCALE*s*qp into out[tok] — atomics now
//    scattered over 131K addresses (~2.3 each, no contention).
//  - Main kernel per wave: 2 staged LDS buffers (K,Q hi only), 16 S-table
//    loads, 64 MFMAs (was 128), no serial arbiter, no global atomics.
//  - OCCUPANCY LAW (R7-R11): 128 total regs/wave (64 acc + 64) = 4 waves/
//    SIMD cap; anything more halves occupancy. This kernel stays at 64 VGPR.
//  - Fallback (ws too small for any tier): 1-pass + inline ref_sign.

#define DIM        128
#define NPROJ      256
#define TILE_T     32
#define NWG        4096        // NTOK / TILE_T
#define LDS_STRIDE 136         // bf16 elems; m97-proven padded layout
#define TAU_W      0.125f      // ~7 sigma of 1-pass bf16 dot error [R12-validated]
#define SCALE      0.0048957583489668f  // sqrt(pi/2)/256

typedef __attribute__((ext_vector_type(8))) short short8;  // 8 bf16 = 4 VGPRs
typedef __attribute__((ext_vector_type(4))) float f32x4;

static __device__ __forceinline__ unsigned short bf16_rne(float x){
    unsigned int u = __builtin_bit_cast(unsigned int, x);
    u += 0x7FFFu + ((u >> 16) & 1u);
    return (unsigned short)(u >> 16);
}

// Reference-exact sign: OpenBLAS sgemm per-element k-chain, fp32 FMA,
// ascending d. Returns np.sign(dot) in {-1, 0, +1}.  [verified round 5]
// The sequential order is the correctness contract — do not reorder.
static __device__ __attribute__((noinline))
float ref_sign(const float* __restrict__ Kg, const float* __restrict__ S,
               int tok, int m){
    const float4* kr = (const float4*)(Kg + (size_t)tok * DIM);
    const float4* sr = (const float4*)(S  + (size_t)m   * DIM);
    float acc = 0.f;
#pragma unroll 4
    for (int d = 0; d < DIM/4; ++d){
        float4 k4 = kr[d];
        float4 s4 = sr[d];
        acc = __builtin_fmaf(k4.x, s4.x, acc);
        acc = __builtin_fmaf(k4.y, s4.y, acc);
        acc = __builtin_fmaf(k4.z, s4.z, acc);
        acc = __builtin_fmaf(k4.w, s4.w, acc);
    }
    return (acc > 0.f) ? 1.f : ((acc < 0.f) ? -1.f : 0.f);
}

// S -> bf16 hi table, swizzled to fragment order:
//   tab[(((g*4+ks)*4+ms)*64 + lane)*8 + e] = conv(S[g*64+ms*16+(lane&15)]
//                                                  [ks*32+(lane>>4)*8+e])
// Also zeroes the per-block record counts (4096 threads == NWG).
__global__ void prep_s_kernel(const float* __restrict__ S,
                              unsigned short* __restrict__ shi,
                              unsigned int* __restrict__ counts){
    int t    = blockIdx.x * 256 + threadIdx.x;   // 4096 threads
    counts[t] = 0u;
    int lane = t & 63;
    int ms   = (t >> 6) & 3;
    int ks   = (t >> 8) & 3;
    int g    = (t >> 10) & 3;
    int m    = g*64 + ms*16 + (lane & 15);
    int d    = ks*32 + (lane >> 4)*8;
    const float4* p = (const float4*)(S + (size_t)m*DIM + d);
    float4 x0 = p[0], x1 = p[1];
    float xs[8] = {x0.x,x0.y,x0.z,x0.w, x1.x,x1.y,x1.z,x1.w};
    size_t base = ((size_t)t) * 8;
    unsigned long long h0=0, h1=0;
#pragma unroll
    for (int e = 0; e < 4; ++e)
        h0 |= (unsigned long long)bf16_rne(xs[e])   << (16*e);
#pragma unroll
    for (int e = 0; e < 4; ++e)
        h1 |= (unsigned long long)bf16_rne(xs[4+e]) << (16*e);
    *(unsigned long long*)(shi + base)     = h0;
    *(unsigned long long*)(shi + base + 4) = h1;
}

// Load this wave's hi A-fragments for one ks: table path (coalesced 16B/lane)
// or inline-convert fallback from fp32 S.
template<bool USE_TAB>
static __device__ __forceinline__
void load_afrags(const unsigned short* __restrict__ shi_tab,
                 const float* __restrict__ S,
                 int wave, int ks, int l16, int quad, int lane,
                 short8 ah[4]){
    if (USE_TAB){
#pragma unroll
        for (int ms = 0; ms < 4; ++ms){
            size_t off = ((size_t)((wave*4 + ks)*4 + ms)*64 + lane)*8;
            ah[ms] = *(const short8*)(shi_tab + off);
        }
    } else {
#pragma unroll
        for (int ms = 0; ms < 4; ++ms){
            const float4* p = (const float4*)(S + (size_t)(wave*64 + ms*16 + l16)*DIM
                                              + ks*32 + quad*8);
            float4 x0 = p[0], x1 = p[1];
            float xs[8] = {x0.x,x0.y,x0.z,x0.w, x1.x,x1.y,x1.z,x1.w};
            short8 h;
#pragma unroll
            for (int e = 0; e < 8; ++e)
                h[e] = (short)bf16_rne(xs[e]);
            ah[ms] = h;
        }
    }
}

template<bool USE_TAB>
__global__ __launch_bounds__(256, 4)
void qjl_kernel(const float* __restrict__ Qg, const float* __restrict__ Kg,
                const float* __restrict__ S,
                const unsigned short* __restrict__ shi_tab,
                unsigned int* __restrict__ counts,
                unsigned long long* __restrict__ records,
                unsigned int bcap,
                float* __restrict__ out)
{
    __shared__ unsigned short khi[TILE_T * LDS_STRIDE];
    __shared__ unsigned short qhi[TILE_T * LDS_STRIDE];
    __shared__ float red[4][TILE_T];
    __shared__ unsigned int bcnt;

    const int tid  = threadIdx.x;
    const int wave = tid >> 6;
    const int lane = tid & 63;
    const int l16  = lane & 15;
    const int quad = lane >> 4;
    const int tok0 = blockIdx.x * TILE_T;

    if (tid == 0) bcnt = 0u;

    // ---- stage: 32 tokens of K and Q, fp32 -> bf16 hi in LDS ----
    {
        const float4* ksrc = (const float4*)(Kg + (size_t)tok0 * DIM);
        const float4* qsrc = (const float4*)(Qg + (size_t)tok0 * DIM);
        float4 kv[4], qv[4];
#pragma unroll
        for (int j = 0; j < 4; ++j){ kv[j] = ksrc[tid + j*256]; qv[j] = qsrc[tid + j*256]; }
#pragma unroll
        for (int j = 0; j < 4; ++j){
            int i   = tid + j*256;
            int row = i >> 5;
            int c   = i & 31;
            float kx[4] = {kv[j].x, kv[j].y, kv[j].z, kv[j].w};
            float qx[4] = {qv[j].x, qv[j].y, qv[j].z, qv[j].w};
            unsigned long long hp = 0, qp = 0;
#pragma unroll
            for (int e = 0; e < 4; ++e){
                hp |= (unsigned long long)bf16_rne(kx[e]) << (16*e);
                qp |= (unsigned long long)bf16_rne(qx[e]) << (16*e);
            }
            int base = row * LDS_STRIDE + c*4;
            *(unsigned long long*)(khi + base) = hp;
            *(unsigned long long*)(qhi + base) = qp;
        }
    }
    __syncthreads();

    // ---- fused k-loop: accC = K·S^T (1-pass), accQ = Q·S^T (1-pass) ----
    f32x4 accC[4][2];
    f32x4 accQ[4][2];
#pragma unroll
    for (int ms = 0; ms < 4; ++ms)
#pragma unroll
        for (int ts = 0; ts < 2; ++ts){
            accC[ms][ts] = (f32x4){0.f,0.f,0.f,0.f};
            accQ[ms][ts] = (f32x4){0.f,0.f,0.f,0.f};
        }

#pragma unroll
    for (int ks = 0; ks < 4; ++ks){
        short8 ah[4];
        load_afrags<USE_TAB>(shi_tab, S, wave, ks, l16, quad, lane, ah);
#pragma unroll
        for (int ts = 0; ts < 2; ++ts){
            const int off = (ts*16 + l16) * LDS_STRIDE + ks*32 + quad*8;
            short8 bk = *(const short8*)(khi + off);
            short8 bq = *(const short8*)(qhi + off);
#pragma unroll
            for (int ms = 0; ms < 4; ++ms)
                accC[ms][ts] = __builtin_amdgcn_mfma_f32_16x16x32_bf16(ah[ms], bk, accC[ms][ts], 0,0,0);
#pragma unroll
            for (int ms = 0; ms < 4; ++ms)
                accQ[ms][ts] = __builtin_amdgcn_mfma_f32_16x16x32_bf16(ah[ms], bq, accQ[ms][ts], 0,0,0);
        }
    }

    // ---- epilogue: sign from 1-pass accC; |C| < TAU_W -> record into this
    //      block's private region via LDS counter (no global atomics).
    //      C/D layout: col(token)=lane&15, row(m)=quad*4+r ----
    float part0 = 0.f, part1 = 0.f;
#pragma unroll
    for (int ts = 0; ts < 2; ++ts){
#pragma unroll
        for (int ms = 0; ms < 4; ++ms){
#pragma unroll
            for (int r = 0; r < 4; ++r){
                float c  = accC[ms][ts][r];
                float qp = accQ[ms][ts][r];
                float sv;
                if (__builtin_fabsf(c) >= TAU_W){
                    sv = (c > 0.f) ? qp : -qp;   // c != 0 here
                } else {
                    int tok = tok0 + ts*16 + l16;
                    int m   = wave*64 + ms*16 + quad*4 + r;
                    if (USE_TAB){
                        unsigned int idx = atomicAdd(&bcnt, 1u);   // LDS atomic
                        if (idx < bcap){
                            unsigned int key = ((unsigned int)tok << 8) | (unsigned int)m;
                            records[(size_t)blockIdx.x * bcap + idx] =
                                ((unsigned long long)__builtin_bit_cast(unsigned int, qp) << 32)
                                | (unsigned long long)key;
                            sv = 0.f;
                        } else {
                            float s = ref_sign(Kg, S, tok, m);   // overflow safety net
                            sv = s * qp;
                        }
                    } else {
                        float s = ref_sign(Kg, S, tok, m);       // no-workspace path
                        sv = s * qp;
                    }
                }
                if (ts) part1 += sv; else part0 += sv;
            }
        }
    }

    // ---- reduce: token t in lanes {l16, l16+16, l16+32, l16+48} ----
    part0 += __shfl_xor(part0, 16, 64);
    part0 += __shfl_xor(part0, 32, 64);
    part1 += __shfl_xor(part1, 16, 64);
    part1 += __shfl_xor(part1, 32, 64);
    if (quad == 0){
        red[wave][l16]      = part0;
        red[wave][16 + l16] = part1;
    }
    __syncthreads();
    if (tid < TILE_T)
        out[tok0 + tid] = SCALE * (red[0][tid] + red[1][tid] + red[2][tid] + red[3][tid]);
    if (USE_TAB && tid == 64)
        counts[blockIdx.x] = (bcnt < bcap) ? bcnt : bcap;
}

// Resolve recorded borderline signs with the exact reference chain, in
// parallel (thread j of block b handles record j), accumulate into out.
// Atomics scatter over ~131K distinct out addresses -> no contention.
__global__ void fixup_kernel(const float* __restrict__ Kg,
                             const float* __restrict__ S,
                             const unsigned int* __restrict__ counts,
                             const unsigned long long* __restrict__ records,
                             unsigned int bcap,
                             float* __restrict__ out){
    unsigned int b = blockIdx.x;
    unsigned int j = threadIdx.x;
    unsigned int n = counts[b];          // already capped at bcap
    if (j >= n) return;
    unsigned long long rec = records[(size_t)b * bcap + j];
    unsigned int key = (unsigned int)rec;
    float qp = __builtin_bit_cast(float, (unsigned int)(rec >> 32));
    int tok = (int)(key >> 8);
    int m   = (int)(key & 255u);
    float s = ref_sign(Kg, S, tok, m);
    if (s != 0.f)
        atomicAdd(&out[tok], SCALE * s * qp);
}

extern "C" void kernel_launch(void* const* d_in, const int* in_sizes, int n_in,
                              void* d_out, int out_size, void* d_ws, size_t ws_size,
                              hipStream_t stream){
    const float* Qg = (const float*)d_in[0];
    const float* Kg = (const float*)d_in[1];
    const float* S  = (const float*)d_in[2];
    float* out = (float*)d_out;

    const size_t tab_bytes    = (size_t)NPROJ * DIM * sizeof(unsigned short); // 64 KiB
    const size_t counts_bytes = (size_t)NWG * sizeof(unsigned int);           // 16 KiB
    const size_t fixed_bytes  = tab_bytes + counts_bytes;                     // 80 KiB

    // Tiered per-block record capacity by available workspace.
    unsigned int bcap = 0;
    if (d_ws && ws_size > fixed_bytes){
        size_t avail = ws_size - fixed_bytes;
        const unsigned int tiers[4] = {128u, 64u, 32u, 16u};
        for (int i = 0; i < 4; ++i){
            if (avail >= (size_t)NWG * tiers[i] * 8u){ bcap = tiers[i]; break; }
        }
    }

    if (bcap){
        unsigned short* shi = (unsigned short*)d_ws;
        unsigned int* counts = (unsigned int*)((char*)d_ws + tab_bytes);
        unsigned long long* recs = (unsigned long long*)((char*)d_ws + fixed_bytes);
        prep_s_kernel<<<16, 256, 0, stream>>>(S, shi, counts);
        qjl_kernel<true><<<NWG, 256, 0, stream>>>(Qg, Kg, S, shi, counts, recs, bcap, out);
        fixup_kernel<<<NWG, 128, 0, stream>>>(Kg, S, counts, recs, bcap, out);
    } else {
        qjl_kernel<false><<<NWG, 256, 0, stream>>>(Qg, Kg, S, nullptr, nullptr, nullptr, 0u, out);
    }
}